// Round 1
// baseline (539.180 us; speedup 1.0000x reference)
//
#include <hip/hip_runtime.h>
#include <hip/hip_bf16.h>

typedef __bf16 bf16;
typedef bf16 bf16x8 __attribute__((ext_vector_type(8)));
typedef bf16 bf16x4 __attribute__((ext_vector_type(4)));
typedef float f32x4 __attribute__((ext_vector_type(4)));

#define SEQ 2048
#define HID 2048

__device__ __forceinline__ void gload16(const bf16* gsrc, bf16* ldst) {
  __builtin_amdgcn_global_load_lds(
      (const __attribute__((address_space(1))) unsigned int*)gsrc,
      (__attribute__((address_space(3))) unsigned int*)ldst, 16, 0, 0);
}

__device__ __forceinline__ f32x4 mfma16(bf16x8 a, bf16x8 b, f32x4 c) {
  return __builtin_amdgcn_mfma_f32_16x16x32_bf16(a, b, c, 0, 0, 0);
}

// ---------------- cast f32 -> bf16 (vectorized) ----------------
__global__ void cast_bf16(const float* __restrict__ in, bf16* __restrict__ out, int n4) {
  int i = blockIdx.x * 256 + threadIdx.x;
  if (i >= n4) return;
  float4 v = ((const float4*)in)[i];
  bf16x4 o = { (bf16)v.x, (bf16)v.y, (bf16)v.z, (bf16)v.w };
  *(bf16x4*)(out + (size_t)i * 4) = o;
}

// ---------------- rope cos/sin table ----------------
__global__ void rope_table(float2* __restrict__ tab) {
  int i = blockIdx.x * 256 + threadIdx.x;   // 0..262143
  int s = i >> 7, dp = i & 127;
  float invf = powf(10000.0f, -(float)dp * (1.0f / 128.0f));
  float f = (float)s * invf;
  tab[i] = make_float2(cosf(f), sinf(f));
}

// ---------------- rope apply, in place on [4096][H*256] bf16 ----------------
template <int H>
__global__ void rope_apply(bf16* __restrict__ X, const float2* __restrict__ tab) {
  int i = blockIdx.x * 256 + threadIdx.x;
  int dp = i & 127;
  int t = i >> 7;              // t = row*H + h
  int h = t & (H - 1);
  int row = t / H;             // row = b*SEQ + s
  int s = row & (SEQ - 1);
  size_t base = (size_t)row * (H * 256) + h * 256;
  float2 cs = tab[s * 128 + dp];
  float x1 = (float)X[base + dp], x2 = (float)X[base + dp + 128];
  X[base + dp]       = (bf16)(x1 * cs.x - x2 * cs.y);
  X[base + dp + 128] = (bf16)(x2 * cs.x + x1 * cs.y);
}

// ---------------- GEMM: C[M][N] = A[M][K] @ B[N][K]^T ----------------
// EPI 0: bf16 row-major out.  EPI 1: V-transpose out Vt[b][kv][d][s].  EPI 2: f32 out.
template <int EPI>
__global__ void gemm_bt(const bf16* __restrict__ A, const bf16* __restrict__ B,
                        void* __restrict__ C, int M, int N, int K) {
  __shared__ __align__(16) bf16 la[128 * 64];
  __shared__ __align__(16) bf16 lb[128 * 64];
  const int tid = threadIdx.x;
  const int w = tid >> 6, l = tid & 63;
  const int lr = l & 15, lg = l >> 4;
  const int brow = blockIdx.x * 128, bcol = blockIdx.y * 128;
  const int wr = w >> 1, wc = w & 1;
  f32x4 acc[4][4];
  const f32x4 zero = {0.f, 0.f, 0.f, 0.f};
#pragma unroll
  for (int m = 0; m < 4; ++m)
#pragma unroll
    for (int n = 0; n < 4; ++n) acc[m][n] = zero;

  for (int k0 = 0; k0 < K; k0 += 64) {
#pragma unroll
    for (int p = 0; p < 4; ++p) {
      int gid = (p * 4 + w) * 64 + l;           // granule id, 16B each
      int row = gid >> 3, col = (gid & 7) * 8;  // [128][64] bf16 tile
      gload16(&A[(size_t)(brow + row) * K + k0 + col], &la[(size_t)(p * 4 + w) * 512]);
      gload16(&B[(size_t)(bcol + row) * K + k0 + col], &lb[(size_t)(p * 4 + w) * 512]);
    }
    __syncthreads();
#pragma unroll
    for (int kk = 0; kk < 2; ++kk) {
      bf16x8 af[4], bfr[4];
#pragma unroll
      for (int m = 0; m < 4; ++m)
        af[m] = *(const bf16x8*)&la[(wr * 64 + m * 16 + lr) * 64 + kk * 32 + lg * 8];
#pragma unroll
      for (int n = 0; n < 4; ++n)
        bfr[n] = *(const bf16x8*)&lb[(wc * 64 + n * 16 + lr) * 64 + kk * 32 + lg * 8];
#pragma unroll
      for (int m = 0; m < 4; ++m)
#pragma unroll
        for (int n = 0; n < 4; ++n)
          acc[m][n] = mfma16(af[m], bfr[n], acc[m][n]);
    }
    __syncthreads();
  }

#pragma unroll
  for (int m = 0; m < 4; ++m) {
#pragma unroll
    for (int n = 0; n < 4; ++n) {
#pragma unroll
      for (int r = 0; r < 4; ++r) {
        int grow = brow + wr * 64 + m * 16 + lg * 4 + r;
        int gcol = bcol + wc * 64 + n * 16 + lr;
        float v = acc[m][n][r];
        if constexpr (EPI == 0) {
          ((bf16*)C)[(size_t)grow * N + gcol] = (bf16)v;
        } else if constexpr (EPI == 1) {
          int b = grow >> 11, s = grow & (SEQ - 1);
          int kv = gcol >> 8, d = gcol & 255;
          ((bf16*)C)[(((size_t)(b * 2 + kv)) * 256 + d) * SEQ + s] = (bf16)v;
        } else {
          ((float*)C)[(size_t)grow * N + gcol] = v;
        }
      }
    }
  }
}

// ---------------- attention ----------------
// grid.x = b*8+h (16), grid.y = q-tile of 64 (32). 256 threads = 4 waves,
// wave w owns q rows [q0 + w*16, +16). Q frags in registers; K/Vt staged in LDS.
__global__ __launch_bounds__(256, 2)
void attn(const bf16* __restrict__ Qp, const bf16* __restrict__ Kp,
          const bf16* __restrict__ Vt, bf16* __restrict__ Aout) {
  __shared__ __align__(16) bf16 Kl[64 * 256];   // [t][d] 32KB
  __shared__ __align__(16) bf16 Vl[256 * 64];   // [d][t] 32KB
  __shared__ __align__(16) bf16 Pl[64 * 64];    // [q][t]  8KB
  const int tid = threadIdx.x, w = tid >> 6, l = tid & 63;
  const int lr = l & 15, lg = l >> 4;
  const int bh = blockIdx.x;
  const int b = bh >> 3, h = bh & 7, kv = h >> 2;
  const int q0 = blockIdx.y * 64;

  const bf16* qbase = Qp + ((size_t)(b * SEQ + q0 + w * 16 + lr)) * HID + h * 256;
  bf16x8 qf[8];
#pragma unroll
  for (int kc = 0; kc < 8; ++kc) qf[kc] = *(const bf16x8*)(qbase + kc * 32 + lg * 8);

  const f32x4 zero = {0.f, 0.f, 0.f, 0.f};
  f32x4 outa[16];
#pragma unroll
  for (int n = 0; n < 16; ++n) outa[n] = zero;
  float rs[4] = {0.f, 0.f, 0.f, 0.f};

  const bf16* kslab = Kp + (size_t)(b * SEQ) * 512 + kv * 256;
  const bf16* vslab = Vt + (size_t)((b * 2 + kv) * 256) * SEQ;

  for (int kt = 0; kt < 32; ++kt) {
    const int t0 = kt * 64;
#pragma unroll
    for (int p = 0; p < 8; ++p) {
      int gid = p * 256 + w * 64 + l;
      // K tile [64][256]: row t = gid>>5, 32 granules per row
      gload16(kslab + (size_t)(t0 + (gid >> 5)) * 512 + (gid & 31) * 8,
              &Kl[(p * 256 + w * 64) * 8]);
      // Vt tile [256][64]: row d = gid>>3, 8 granules per row
      gload16(vslab + (size_t)(gid >> 3) * SEQ + t0 + (gid & 7) * 8,
              &Vl[(p * 256 + w * 64) * 8]);
    }
    __syncthreads();

    f32x4 sc[4];
#pragma unroll
    for (int n = 0; n < 4; ++n) sc[n] = zero;
#pragma unroll
    for (int kc = 0; kc < 8; ++kc) {
#pragma unroll
      for (int n = 0; n < 4; ++n) {
        bf16x8 kf = *(const bf16x8*)&Kl[(n * 16 + lr) * 256 + kc * 32 + lg * 8];
        sc[n] = mfma16(qf[kc], kf, sc[n]);
      }
    }

    // softcap + exp with fixed max 50: p = exp(50*tanh(s/50) - 50) = exp(-100/(e^{s/25}+1))
#pragma unroll
    for (int n = 0; n < 4; ++n) {
#pragma unroll
      for (int r = 0; r < 4; ++r) {
        float s = sc[n][r] * 0.0625f;
        float e1 = __expf(s * 0.04f);
        float p = __expf(-100.0f / (e1 + 1.0f));
        rs[r] += p;
        Pl[(w * 16 + lg * 4 + r) * 64 + n * 16 + lr] = (bf16)p;
      }
    }

    // PV: out += P[16q][64t] @ Vt[256d][64t]^T
#pragma unroll
    for (int kc2 = 0; kc2 < 2; ++kc2) {
      bf16x8 pf = *(const bf16x8*)&Pl[(w * 16 + lr) * 64 + kc2 * 32 + lg * 8];
#pragma unroll
      for (int n = 0; n < 16; ++n) {
        bf16x8 vf = *(const bf16x8*)&Vl[(n * 16 + lr) * 64 + kc2 * 32 + lg * 8];
        outa[n] = mfma16(pf, vf, outa[n]);
      }
    }
    __syncthreads();
  }

  // rowsum reduce within 16-lane group, then normalize + write
  float inv[4];
#pragma unroll
  for (int r = 0; r < 4; ++r) {
    float v = rs[r];
    v += __shfl_xor(v, 1, 16);
    v += __shfl_xor(v, 2, 16);
    v += __shfl_xor(v, 4, 16);
    v += __shfl_xor(v, 8, 16);
    inv[r] = 1.0f / v;
  }
  bf16* obase = Aout + ((size_t)(b * SEQ + q0 + w * 16 + lg * 4)) * HID + h * 256 + lr;
#pragma unroll
  for (int n = 0; n < 16; ++n)
#pragma unroll
    for (int r = 0; r < 4; ++r)
      obase[(size_t)r * HID + n * 16] = (bf16)(outa[n][r] * inv[r]);
}

// ---------------- launch ----------------
extern "C" void kernel_launch(void* const* d_in, const int* in_sizes, int n_in,
                              void* d_out, int out_size, void* d_ws, size_t ws_size,
                              hipStream_t stream) {
  const float* hs = (const float*)d_in[0];
  const float* Wq = (const float*)d_in[1];
  const float* Wk = (const float*)d_in[2];
  const float* Wv = (const float*)d_in[3];
  const float* Wo = (const float*)d_in[4];
  float* out = (float*)d_out;
  char* ws = (char*)d_ws;

  bf16* hs_b  = (bf16*)(ws + 0);          // 16.8MB, reused as attn-out after V GEMM
  bf16* wq_b  = (bf16*)(ws + 16777216);   // 8.4MB
  bf16* wk_b  = (bf16*)(ws + 25165824);   // 2.1MB
  bf16* wv_b  = (bf16*)(ws + 27262976);   // 2.1MB
  bf16* wo_b  = (bf16*)(ws + 29360128);   // 8.4MB
  bf16* qp    = (bf16*)(ws + 37748736);   // 16.8MB  Q proj (roped in place)
  bf16* kp    = (bf16*)(ws + 54525952);   // 4.2MB   K proj (roped in place)
  bf16* vt    = (bf16*)(ws + 58720256);   // 4.2MB   V transposed [b][kv][d][s]
  float2* tab = (float2*)(ws + 62914560); // 2MB     rope table
  bf16* aout  = hs_b;

  cast_bf16<<<8192, 256, 0, stream>>>(hs, hs_b, 2097152);
  cast_bf16<<<4096, 256, 0, stream>>>(Wq, wq_b, 1048576);
  cast_bf16<<<1024, 256, 0, stream>>>(Wk, wk_b, 262144);
  cast_bf16<<<1024, 256, 0, stream>>>(Wv, wv_b, 262144);
  cast_bf16<<<4096, 256, 0, stream>>>(Wo, wo_b, 1048576);
  rope_table<<<1024, 256, 0, stream>>>(tab);

  gemm_bt<0><<<dim3(32, 16), 256, 0, stream>>>(hs_b, wq_b, qp, 4096, 2048, 2048);
  gemm_bt<0><<<dim3(32, 4),  256, 0, stream>>>(hs_b, wk_b, kp, 4096, 512, 2048);
  gemm_bt<1><<<dim3(32, 4),  256, 0, stream>>>(hs_b, wv_b, vt, 4096, 512, 2048);

  rope_apply<8><<<16384, 256, 0, stream>>>(qp, tab);
  rope_apply<2><<<4096, 256, 0, stream>>>(kp, tab);

  attn<<<dim3(16, 32), 256, 0, stream>>>(qp, kp, vt, aout);

  gemm_bt<2><<<dim3(32, 16), 256, 0, stream>>>(aout, wo_b, out, 4096, 2048, 2048);
}

// Round 5
// 415.851 us; speedup vs baseline: 1.2966x; 1.2966x over previous
//
#include <hip/hip_runtime.h>
#include <hip/hip_bf16.h>

typedef __bf16 bf16;
typedef bf16 bf16x8 __attribute__((ext_vector_type(8)));
typedef bf16 bf16x4 __attribute__((ext_vector_type(4)));
typedef float f32x4 __attribute__((ext_vector_type(4)));

#define SEQ 2048
#define HID 2048

__device__ __forceinline__ void gload16(const bf16* gsrc, bf16* ldst) {
  __builtin_amdgcn_global_load_lds(
      (const __attribute__((address_space(1))) unsigned int*)gsrc,
      (__attribute__((address_space(3))) unsigned int*)ldst, 16, 0, 0);
}

__device__ __forceinline__ f32x4 mfma16(bf16x8 a, bf16x8 b, f32x4 c) {
  return __builtin_amdgcn_mfma_f32_16x16x32_bf16(a, b, c, 0, 0, 0);
}

// ---------------- cast f32 -> bf16 (vectorized) ----------------
__global__ void cast_bf16(const float* __restrict__ in, bf16* __restrict__ out, int n4) {
  int i = blockIdx.x * 256 + threadIdx.x;
  if (i >= n4) return;
  float4 v = ((const float4*)in)[i];
  bf16x4 o = { (bf16)v.x, (bf16)v.y, (bf16)v.z, (bf16)v.w };
  *(bf16x4*)(out + (size_t)i * 4) = o;
}

// ---------------- rope cos/sin table ----------------
__global__ void rope_table(float2* __restrict__ tab) {
  int i = blockIdx.x * 256 + threadIdx.x;   // 0..262143
  int s = i >> 7, dp = i & 127;
  float invf = powf(10000.0f, -(float)dp * (1.0f / 128.0f));
  float f = (float)s * invf;
  tab[i] = make_float2(cosf(f), sinf(f));
}

// ---------------- rope apply, in place on [4096][H*256] bf16 ----------------
template <int H>
__global__ void rope_apply(bf16* __restrict__ X, const float2* __restrict__ tab) {
  int i = blockIdx.x * 256 + threadIdx.x;
  int dp = i & 127;
  int t = i >> 7;              // t = row*H + h
  int h = t & (H - 1);
  int row = t / H;             // row = b*SEQ + s
  int s = row & (SEQ - 1);
  size_t base = (size_t)row * (H * 256) + h * 256;
  float2 cs = tab[s * 128 + dp];
  float x1 = (float)X[base + dp], x2 = (float)X[base + dp + 128];
  X[base + dp]       = (bf16)(x1 * cs.x - x2 * cs.y);
  X[base + dp + 128] = (bf16)(x2 * cs.x + x1 * cs.y);
}

// ---------------- GEMM: C[M][N] = A[M][K] @ B[N][K]^T ----------------
// EPI 0: bf16 row-major out.  EPI 1: V-transpose out Vt[b][kv][d][s].  EPI 2: f32 out.
template <int EPI>
__global__ void gemm_bt(const bf16* __restrict__ A, const bf16* __restrict__ B,
                        void* __restrict__ C, int M, int N, int K) {
  __shared__ __align__(16) bf16 la[128 * 64];
  __shared__ __align__(16) bf16 lb[128 * 64];
  const int tid = threadIdx.x;
  const int w = tid >> 6, l = tid & 63;
  const int lr = l & 15, lg = l >> 4;
  const int brow = blockIdx.x * 128, bcol = blockIdx.y * 128;
  const int wr = w >> 1, wc = w & 1;
  f32x4 acc[4][4];
  const f32x4 zero = {0.f, 0.f, 0.f, 0.f};
#pragma unroll
  for (int m = 0; m < 4; ++m)
#pragma unroll
    for (int n = 0; n < 4; ++n) acc[m][n] = zero;

  for (int k0 = 0; k0 < K; k0 += 64) {
#pragma unroll
    for (int p = 0; p < 4; ++p) {
      int gid = (p * 4 + w) * 64 + l;           // granule id, 16B each
      int row = gid >> 3, col = (gid & 7) * 8;  // [128][64] bf16 tile
      gload16(&A[(size_t)(brow + row) * K + k0 + col], &la[(size_t)(p * 4 + w) * 512]);
      gload16(&B[(size_t)(bcol + row) * K + k0 + col], &lb[(size_t)(p * 4 + w) * 512]);
    }
    __syncthreads();
#pragma unroll
    for (int kk = 0; kk < 2; ++kk) {
      bf16x8 af[4], bfr[4];
#pragma unroll
      for (int m = 0; m < 4; ++m)
        af[m] = *(const bf16x8*)&la[(wr * 64 + m * 16 + lr) * 64 + kk * 32 + lg * 8];
#pragma unroll
      for (int n = 0; n < 4; ++n)
        bfr[n] = *(const bf16x8*)&lb[(wc * 64 + n * 16 + lr) * 64 + kk * 32 + lg * 8];
#pragma unroll
      for (int m = 0; m < 4; ++m)
#pragma unroll
        for (int n = 0; n < 4; ++n)
          acc[m][n] = mfma16(af[m], bfr[n], acc[m][n]);
    }
    __syncthreads();
  }

#pragma unroll
  for (int m = 0; m < 4; ++m) {
#pragma unroll
    for (int n = 0; n < 4; ++n) {
#pragma unroll
      for (int r = 0; r < 4; ++r) {
        int grow = brow + wr * 64 + m * 16 + lg * 4 + r;
        int gcol = bcol + wc * 64 + n * 16 + lr;
        float v = acc[m][n][r];
        if constexpr (EPI == 0) {
          ((bf16*)C)[(size_t)grow * N + gcol] = (bf16)v;
        } else if constexpr (EPI == 1) {
          int b = grow >> 11, s = grow & (SEQ - 1);
          int kv = gcol >> 8, d = gcol & 255;
          ((bf16*)C)[(((size_t)(b * 2 + kv)) * 256 + d) * SEQ + s] = (bf16)v;
        } else {
          ((float*)C)[(size_t)grow * N + gcol] = v;
        }
      }
    }
  }
}

// ---------------- attention ----------------
// 1D grid of 512 blocks, XCD-remapped so each XCD owns 2 bh values (K/V slabs
// fit its 4MB L2). 256 threads = 4 waves, wave w owns q rows [q0+w*16, +16).
// Q frags in registers; K/Vt staged in LDS via global_load_lds with the XOR
// swizzle applied to the GLOBAL source granule (rule #21: linear LDS dest +
// inverse-swizzled source + swizzled read). P swizzled on write+read.
__global__ __launch_bounds__(256, 2)
void attn(const bf16* __restrict__ Qp, const bf16* __restrict__ Kp,
          const bf16* __restrict__ Vt, bf16* __restrict__ Aout) {
  __shared__ __align__(16) bf16 Kl[64 * 256];   // [t][d] 32KB, swizzled
  __shared__ __align__(16) bf16 Vl[256 * 64];   // [d][t] 32KB, swizzled
  __shared__ __align__(16) bf16 Pl[64 * 64];    // [q][t]  8KB, swizzled
  const int tid = threadIdx.x, w = tid >> 6, l = tid & 63;
  const int lr = l & 15, lg = l >> 4;
  // XCD remap: lin -> (xcd = lin&7, slot = lin>>3); work = xcd*64+slot.
  const int lin = blockIdx.x;
  const int work = (lin & 7) * 64 + (lin >> 3);
  const int bh = work >> 5;
  const int b = bh >> 3, h = bh & 7, kv = h >> 2;
  const int q0 = (work & 31) * 64;

  const bf16* qbase = Qp + ((size_t)(b * SEQ + q0 + w * 16 + lr)) * HID + h * 256;
  bf16x8 qf[8];
#pragma unroll
  for (int kc = 0; kc < 8; ++kc) qf[kc] = *(const bf16x8*)(qbase + kc * 32 + lg * 8);

  const f32x4 zero = {0.f, 0.f, 0.f, 0.f};
  f32x4 outa[16];
#pragma unroll
  for (int n = 0; n < 16; ++n) outa[n] = zero;
  float rs[4] = {0.f, 0.f, 0.f, 0.f};

  const bf16* kslab = Kp + (size_t)(b * SEQ) * 512 + kv * 256;
  const bf16* vslab = Vt + (size_t)((b * 2 + kv) * 256) * SEQ;

  for (int kt = 0; kt < 32; ++kt) {
    const int t0 = kt * 64;
#pragma unroll
    for (int p = 0; p < 8; ++p) {
      int gid = p * 256 + w * 64 + l;
      // K tile [64][256]: 32 granules/row; source granule = g ^ (row&7)
      {
        int row = gid >> 5, g = gid & 31;
        gload16(kslab + (size_t)(t0 + row) * 512 + ((g ^ (row & 7)) * 8),
                &Kl[(p * 256 + w * 64) * 8]);
      }
      // Vt tile [256][64]: 8 granules/row; source granule = g ^ (row&7)
      {
        int row = gid >> 3, g = gid & 7;
        gload16(vslab + (size_t)row * SEQ + t0 + ((g ^ (row & 7)) * 8),
                &Vl[(p * 256 + w * 64) * 8]);
      }
    }
    __syncthreads();

    f32x4 sc[4];
#pragma unroll
    for (int n = 0; n < 4; ++n) sc[n] = zero;
#pragma unroll
    for (int kc = 0; kc < 8; ++kc) {
#pragma unroll
      for (int n = 0; n < 4; ++n) {
        // swizzled read: granule (kc*4+lg) ^ (row&7), row = n*16+lr
        bf16x8 kf = *(const bf16x8*)&Kl[(n * 16 + lr) * 256 + (((kc * 4 + lg) ^ (lr & 7)) * 8)];
        sc[n] = mfma16(qf[kc], kf, sc[n]);
      }
    }

    // softcap + exp with fixed max 50: p = exp(50*tanh(s/50) - 50) = exp(-100/(e^{s/25}+1))
    // s = raw * 0.0625; fold: e1 = exp(raw * 0.0025)
#pragma unroll
    for (int n = 0; n < 4; ++n) {
#pragma unroll
      for (int r = 0; r < 4; ++r) {
        float e1 = __expf(sc[n][r] * 0.0025f);
        float p = __expf(-100.0f * __builtin_amdgcn_rcpf(e1 + 1.0f));
        rs[r] += p;
        int prow = w * 16 + lg * 4 + r;
        int pcol = (n * 16 + lr) ^ ((prow & 7) << 3);   // swizzled write
        Pl[prow * 64 + pcol] = (bf16)p;
      }
    }

    // PV: out += P[16q][64t] @ Vt[256d][64t]^T
#pragma unroll
    for (int kc2 = 0; kc2 < 2; ++kc2) {
      bf16x8 pf = *(const bf16x8*)&Pl[(w * 16 + lr) * 64 + (((kc2 * 4 + lg) ^ (lr & 7)) * 8)];
#pragma unroll
      for (int n = 0; n < 16; ++n) {
        bf16x8 vf = *(const bf16x8*)&Vl[(n * 16 + lr) * 64 + (((kc2 * 4 + lg) ^ (lr & 7)) * 8)];
        outa[n] = mfma16(pf, vf, outa[n]);
      }
    }
    __syncthreads();
  }

  // rowsum reduce within 16-lane group, then normalize + write
  float inv[4];
#pragma unroll
  for (int r = 0; r < 4; ++r) {
    float v = rs[r];
    v += __shfl_xor(v, 1, 16);
    v += __shfl_xor(v, 2, 16);
    v += __shfl_xor(v, 4, 16);
    v += __shfl_xor(v, 8, 16);
    inv[r] = 1.0f / v;
  }
  bf16* obase = Aout + ((size_t)(b * SEQ + q0 + w * 16 + lg * 4)) * HID + h * 256 + lr;
#pragma unroll
  for (int n = 0; n < 16; ++n)
#pragma unroll
    for (int r = 0; r < 4; ++r)
      obase[(size_t)r * HID + n * 16] = (bf16)(outa[n][r] * inv[r]);
}

// ---------------- launch ----------------
extern "C" void kernel_launch(void* const* d_in, const int* in_sizes, int n_in,
                              void* d_out, int out_size, void* d_ws, size_t ws_size,
                              hipStream_t stream) {
  const float* hs = (const float*)d_in[0];
  const float* Wq = (const float*)d_in[1];
  const float* Wk = (const float*)d_in[2];
  const float* Wv = (const float*)d_in[3];
  const float* Wo = (const float*)d_in[4];
  float* out = (float*)d_out;
  char* ws = (char*)d_ws;

  bf16* hs_b  = (bf16*)(ws + 0);          // 16.8MB, reused as attn-out after V GEMM
  bf16* wq_b  = (bf16*)(ws + 16777216);   // 8.4MB
  bf16* wk_b  = (bf16*)(ws + 25165824);   // 2.1MB
  bf16* wv_b  = (bf16*)(ws + 27262976);   // 2.1MB
  bf16* wo_b  = (bf16*)(ws + 29360128);   // 8.4MB
  bf16* qp    = (bf16*)(ws + 37748736);   // 16.8MB  Q proj (roped in place)
  bf16* kp    = (bf16*)(ws + 54525952);   // 4.2MB   K proj (roped in place)
  bf16* vt    = (bf16*)(ws + 58720256);   // 4.2MB   V transposed [b][kv][d][s]
  float2* tab = (float2*)(ws + 62914560); // 2MB     rope table
  bf16* aout  = hs_b;

  cast_bf16<<<8192, 256, 0, stream>>>(hs, hs_b, 2097152);
  cast_bf16<<<4096, 256, 0, stream>>>(Wq, wq_b, 1048576);
  cast_bf16<<<1024, 256, 0, stream>>>(Wk, wk_b, 262144);
  cast_bf16<<<1024, 256, 0, stream>>>(Wv, wv_b, 262144);
  cast_bf16<<<4096, 256, 0, stream>>>(Wo, wo_b, 1048576);
  rope_table<<<1024, 256, 0, stream>>>(tab);

  gemm_bt<0><<<dim3(32, 16), 256, 0, stream>>>(hs_b, wq_b, qp, 4096, 2048, 2048);
  gemm_bt<0><<<dim3(32, 4),  256, 0, stream>>>(hs_b, wk_b, kp, 4096, 512, 2048);
  gemm_bt<1><<<dim3(32, 4),  256, 0, stream>>>(hs_b, wv_b, vt, 4096, 512, 2048);

  rope_apply<8><<<16384, 256, 0, stream>>>(qp, tab);
  rope_apply<2><<<4096, 256, 0, stream>>>(kp, tab);

  attn<<<512, 256, 0, stream>>>(qp, kp, vt, aout);

  gemm_bt<2><<<dim3(32, 16), 256, 0, stream>>>(aout, wo_b, out, 4096, 2048, 2048);
}

// Round 6
// 395.443 us; speedup vs baseline: 1.3635x; 1.0516x over previous
//
#include <hip/hip_runtime.h>
#include <hip/hip_bf16.h>

typedef __bf16 bf16;
typedef bf16 bf16x8 __attribute__((ext_vector_type(8)));
typedef bf16 bf16x4 __attribute__((ext_vector_type(4)));
typedef float f32x4 __attribute__((ext_vector_type(4)));

#define SEQ 2048
#define HID 2048

__device__ __forceinline__ void gload16(const bf16* gsrc, bf16* ldst) {
  __builtin_amdgcn_global_load_lds(
      (const __attribute__((address_space(1))) unsigned int*)gsrc,
      (__attribute__((address_space(3))) unsigned int*)ldst, 16, 0, 0);
}

__device__ __forceinline__ f32x4 mfma16(bf16x8 a, bf16x8 b, f32x4 c) {
  return __builtin_amdgcn_mfma_f32_16x16x32_bf16(a, b, c, 0, 0, 0);
}

// ---------------- cast f32 -> bf16 (vectorized) ----------------
__global__ void cast_bf16(const float* __restrict__ in, bf16* __restrict__ out, int n4) {
  int i = blockIdx.x * 256 + threadIdx.x;
  if (i >= n4) return;
  float4 v = ((const float4*)in)[i];
  bf16x4 o = { (bf16)v.x, (bf16)v.y, (bf16)v.z, (bf16)v.w };
  *(bf16x4*)(out + (size_t)i * 4) = o;
}

// ---------------- rope cos/sin table ----------------
__global__ void rope_table(float2* __restrict__ tab) {
  int i = blockIdx.x * 256 + threadIdx.x;   // 0..262143
  int s = i >> 7, dp = i & 127;
  float invf = powf(10000.0f, -(float)dp * (1.0f / 128.0f));
  float f = (float)s * invf;
  tab[i] = make_float2(cosf(f), sinf(f));
}

// ---------------- rope apply, in place on [4096][H*256] bf16 ----------------
template <int H>
__global__ void rope_apply(bf16* __restrict__ X, const float2* __restrict__ tab) {
  int i = blockIdx.x * 256 + threadIdx.x;
  int dp = i & 127;
  int t = i >> 7;              // t = row*H + h
  int h = t & (H - 1);
  int row = t / H;             // row = b*SEQ + s
  int s = row & (SEQ - 1);
  size_t base = (size_t)row * (H * 256) + h * 256;
  float2 cs = tab[s * 128 + dp];
  float x1 = (float)X[base + dp], x2 = (float)X[base + dp + 128];
  X[base + dp]       = (bf16)(x1 * cs.x - x2 * cs.y);
  X[base + dp + 128] = (bf16)(x2 * cs.x + x1 * cs.y);
}

// ---------------- GEMM: C[M][N] = A[M][K] @ B[N][K]^T ----------------
// EPI 2: f32 out to C.
// EPI 3: fused QKV routing: gcol<2048 -> q (bf16, C), <2560 -> k (bf16, C2),
//        else -> v transposed Vt[b][kv][d][s] (bf16, C3).
template <int EPI>
__global__ void gemm_bt(const bf16* __restrict__ A, const bf16* __restrict__ B,
                        void* __restrict__ C, void* __restrict__ C2,
                        void* __restrict__ C3, int M, int N, int K) {
  __shared__ __align__(16) bf16 la[128 * 64];
  __shared__ __align__(16) bf16 lb[128 * 64];
  const int tid = threadIdx.x;
  const int w = tid >> 6, l = tid & 63;
  const int lr = l & 15, lg = l >> 4;
  const int brow = blockIdx.x * 128, bcol = blockIdx.y * 128;
  const int wr = w >> 1, wc = w & 1;
  f32x4 acc[4][4];
  const f32x4 zero = {0.f, 0.f, 0.f, 0.f};
#pragma unroll
  for (int m = 0; m < 4; ++m)
#pragma unroll
    for (int n = 0; n < 4; ++n) acc[m][n] = zero;

  for (int k0 = 0; k0 < K; k0 += 64) {
#pragma unroll
    for (int p = 0; p < 4; ++p) {
      int gid = (p * 4 + w) * 64 + l;           // granule id, 16B each
      int row = gid >> 3, col = (gid & 7) * 8;  // [128][64] bf16 tile
      gload16(&A[(size_t)(brow + row) * K + k0 + col], &la[(size_t)(p * 4 + w) * 512]);
      gload16(&B[(size_t)(bcol + row) * K + k0 + col], &lb[(size_t)(p * 4 + w) * 512]);
    }
    __syncthreads();
#pragma unroll
    for (int kk = 0; kk < 2; ++kk) {
      bf16x8 af[4], bfr[4];
#pragma unroll
      for (int m = 0; m < 4; ++m)
        af[m] = *(const bf16x8*)&la[(wr * 64 + m * 16 + lr) * 64 + kk * 32 + lg * 8];
#pragma unroll
      for (int n = 0; n < 4; ++n)
        bfr[n] = *(const bf16x8*)&lb[(wc * 64 + n * 16 + lr) * 64 + kk * 32 + lg * 8];
#pragma unroll
      for (int m = 0; m < 4; ++m)
#pragma unroll
        for (int n = 0; n < 4; ++n)
          acc[m][n] = mfma16(af[m], bfr[n], acc[m][n]);
    }
    __syncthreads();
  }

#pragma unroll
  for (int m = 0; m < 4; ++m) {
#pragma unroll
    for (int n = 0; n < 4; ++n) {
#pragma unroll
      for (int r = 0; r < 4; ++r) {
        int grow = brow + wr * 64 + m * 16 + lg * 4 + r;
        int gcol = bcol + wc * 64 + n * 16 + lr;
        float v = acc[m][n][r];
        if constexpr (EPI == 2) {
          ((float*)C)[(size_t)grow * N + gcol] = v;
        } else {  // EPI == 3, branch is block-uniform (bcol multiple of 128)
          if (gcol < 2048) {
            ((bf16*)C)[(size_t)grow * 2048 + gcol] = (bf16)v;
          } else if (gcol < 2560) {
            ((bf16*)C2)[(size_t)grow * 512 + (gcol - 2048)] = (bf16)v;
          } else {
            int kvcol = gcol - 2560;
            int b = grow >> 11, s = grow & (SEQ - 1);
            int kv = kvcol >> 8, d = kvcol & 255;
            ((bf16*)C3)[(((size_t)(b * 2 + kv)) * 256 + d) * SEQ + s] = (bf16)v;
          }
        }
      }
    }
  }
}

// ---------------- attention ----------------
// grid 256 blocks (XCD-remapped: 2 bh per XCD -> K/V slabs ~4MB fit L2).
// Block: 256 thr = 4 waves; q-tile 128, wave w owns 32 q-rows (2 MFMA m-groups)
// so each kf/vf LDS read feeds 2 MFMAs (halves LDS bytes per FLOP vs 16q/wave).
// K/V double-buffered (T3-minimum: issue STAGE(next) before compute(cur), one
// barrier per kt). P is wave-local (no barrier). LDS = 2*32+2*32+16 = 144 KB,
// 1 block/CU. Swizzles: linear LDS dest + inverse-swizzled global source +
// swizzled read (rule #21), verified in round 5.
__global__ __launch_bounds__(256, 1)
void attn(const bf16* __restrict__ Qp, const bf16* __restrict__ Kp,
          const bf16* __restrict__ Vt, bf16* __restrict__ Aout) {
  __shared__ __align__(16) bf16 Kl[2][64 * 256];   // [t][d] 2x32KB, swizzled
  __shared__ __align__(16) bf16 Vl[2][256 * 64];   // [d][t] 2x32KB, swizzled
  __shared__ __align__(16) bf16 Pl[128 * 64];      // [q][t] 16KB, swizzled
  const int tid = threadIdx.x, w = tid >> 6, l = tid & 63;
  const int lr = l & 15, lg = l >> 4;
  // XCD remap: 256 blocks -> xcd = lin&7 owns works [xcd*32, +32) = 2 bh.
  const int lin = blockIdx.x;
  const int work = (lin & 7) * 32 + (lin >> 3);
  const int bh = work >> 4;                 // 16 q-tiles per bh
  const int b = bh >> 3, h = bh & 7, kv = h >> 2;
  const int q0 = (work & 15) * 128;

  bf16x8 qf[2][8];
#pragma unroll
  for (int m = 0; m < 2; ++m) {
    const bf16* qb = Qp + ((size_t)(b * SEQ + q0 + w * 32 + m * 16 + lr)) * HID + h * 256;
#pragma unroll
    for (int kc = 0; kc < 8; ++kc) qf[m][kc] = *(const bf16x8*)(qb + kc * 32 + lg * 8);
  }

  const f32x4 zero = {0.f, 0.f, 0.f, 0.f};
  f32x4 outa[2][16];
#pragma unroll
  for (int m = 0; m < 2; ++m)
#pragma unroll
    for (int n = 0; n < 16; ++n) outa[m][n] = zero;
  float rs[2][4] = {{0.f, 0.f, 0.f, 0.f}, {0.f, 0.f, 0.f, 0.f}};

  const bf16* kslab = Kp + (size_t)(b * SEQ) * 512 + kv * 256;
  const bf16* vslab = Vt + (size_t)((b * 2 + kv) * 256) * SEQ;

  auto stage = [&](int buf, int ktile) {
    const int t0s = ktile * 64;
#pragma unroll
    for (int p = 0; p < 8; ++p) {
      int gid = p * 256 + tid;
      {  // K tile [64][256]: 32 granules/row; source granule = g ^ (row&7)
        int row = gid >> 5, g = gid & 31;
        gload16(kslab + (size_t)(t0s + row) * 512 + ((g ^ (row & 7)) * 8),
                &Kl[buf][(p * 256 + w * 64) * 8]);
      }
      {  // Vt tile [256][64]: 8 granules/row; source granule = g ^ (row&7)
        int row = gid >> 3, g = gid & 7;
        gload16(vslab + (size_t)row * SEQ + t0s + ((g ^ (row & 7)) * 8),
                &Vl[buf][(p * 256 + w * 64) * 8]);
      }
    }
  };

  stage(0, 0);
  __syncthreads();

  for (int kt = 0; kt < 32; ++kt) {
    const int cur = kt & 1;
    if (kt < 31) stage(cur ^ 1, kt + 1);   // prefetch next tile into other buffer

    // QK^T: each kf feeds both m-groups
    f32x4 sc[2][4];
#pragma unroll
    for (int m = 0; m < 2; ++m)
#pragma unroll
      for (int n = 0; n < 4; ++n) sc[m][n] = zero;
#pragma unroll
    for (int kc = 0; kc < 8; ++kc) {
#pragma unroll
      for (int n = 0; n < 4; ++n) {
        bf16x8 kf = *(const bf16x8*)&Kl[cur][(n * 16 + lr) * 256 + (((kc * 4 + lg) ^ (lr & 7)) * 8)];
        sc[0][n] = mfma16(qf[0][kc], kf, sc[0][n]);
        sc[1][n] = mfma16(qf[1][kc], kf, sc[1][n]);
      }
    }

    // softcap + exp, fixed max 50: p = exp(50*tanh(s/50) - 50) = exp(-100/(e^{s/25}+1))
    // s = raw * 0.0625  ->  e1 = exp(raw * 0.0025)
#pragma unroll
    for (int m = 0; m < 2; ++m) {
#pragma unroll
      for (int n = 0; n < 4; ++n) {
#pragma unroll
        for (int r = 0; r < 4; ++r) {
          float e1 = __expf(sc[m][n][r] * 0.0025f);
          float p = __expf(-100.0f * __builtin_amdgcn_rcpf(e1 + 1.0f));
          rs[m][r] += p;
          int prow = w * 32 + m * 16 + lg * 4 + r;
          int pcol = (n * 16 + lr) ^ ((prow & 7) << 3);   // swizzled write
          Pl[prow * 64 + pcol] = (bf16)p;
        }
      }
    }

    // PV: out += P[32q][64t] @ Vt[256d][64t]^T ; each vf feeds both m-groups
#pragma unroll
    for (int kc2 = 0; kc2 < 2; ++kc2) {
      bf16x8 pf0 = *(const bf16x8*)&Pl[(w * 32 + lr) * 64 + (((kc2 * 4 + lg) ^ (lr & 7)) * 8)];
      bf16x8 pf1 = *(const bf16x8*)&Pl[(w * 32 + 16 + lr) * 64 + (((kc2 * 4 + lg) ^ (lr & 7)) * 8)];
#pragma unroll
      for (int n = 0; n < 16; ++n) {
        bf16x8 vf = *(const bf16x8*)&Vl[cur][(n * 16 + lr) * 64 + (((kc2 * 4 + lg) ^ (lr & 7)) * 8)];
        outa[0][n] = mfma16(pf0, vf, outa[0][n]);
        outa[1][n] = mfma16(pf1, vf, outa[1][n]);
      }
    }
    __syncthreads();   // drains prefetch vmcnt + guards buffer swap
  }

  // rowsum reduce within 16-lane group, normalize, write
#pragma unroll
  for (int m = 0; m < 2; ++m) {
    float inv[4];
#pragma unroll
    for (int r = 0; r < 4; ++r) {
      float v = rs[m][r];
      v += __shfl_xor(v, 1, 16);
      v += __shfl_xor(v, 2, 16);
      v += __shfl_xor(v, 4, 16);
      v += __shfl_xor(v, 8, 16);
      inv[r] = 1.0f / v;
    }
    bf16* ob = Aout + ((size_t)(b * SEQ + q0 + w * 32 + m * 16 + lg * 4)) * HID + h * 256 + lr;
#pragma unroll
    for (int n = 0; n < 16; ++n)
#pragma unroll
      for (int r = 0; r < 4; ++r)
        ob[(size_t)r * HID + n * 16] = (bf16)(outa[m][n][r] * inv[r]);
  }
}

// ---------------- launch ----------------
extern "C" void kernel_launch(void* const* d_in, const int* in_sizes, int n_in,
                              void* d_out, int out_size, void* d_ws, size_t ws_size,
                              hipStream_t stream) {
  const float* hs = (const float*)d_in[0];
  const float* Wq = (const float*)d_in[1];
  const float* Wk = (const float*)d_in[2];
  const float* Wv = (const float*)d_in[3];
  const float* Wo = (const float*)d_in[4];
  float* out = (float*)d_out;
  char* ws = (char*)d_ws;

  bf16* hs_b  = (bf16*)(ws + 0);          // 16.8MB, reused as attn-out after QKV GEMM
  bf16* wq_b  = (bf16*)(ws + 16777216);   // 8.4MB  } contiguous [3072][2048]
  bf16* wk_b  = (bf16*)(ws + 25165824);   // 2.1MB  } for the fused QKV GEMM
  bf16* wv_b  = (bf16*)(ws + 27262976);   // 2.1MB  }
  bf16* wo_b  = (bf16*)(ws + 29360128);   // 8.4MB
  bf16* qp    = (bf16*)(ws + 37748736);   // 16.8MB  Q proj (roped in place)
  bf16* kp    = (bf16*)(ws + 54525952);   // 4.2MB   K proj (roped in place)
  bf16* vt    = (bf16*)(ws + 58720256);   // 4.2MB   V transposed [b][kv][d][s]
  float2* tab = (float2*)(ws + 62914560); // 2MB     rope table
  bf16* aout  = hs_b;

  cast_bf16<<<8192, 256, 0, stream>>>(hs, hs_b, 2097152);
  cast_bf16<<<4096, 256, 0, stream>>>(Wq, wq_b, 1048576);
  cast_bf16<<<1024, 256, 0, stream>>>(Wk, wk_b, 262144);
  cast_bf16<<<1024, 256, 0, stream>>>(Wv, wv_b, 262144);
  cast_bf16<<<4096, 256, 0, stream>>>(Wo, wo_b, 1048576);
  rope_table<<<1024, 256, 0, stream>>>(tab);

  // fused QKV: C[4096][3072] = hs_b @ [wq|wk|wv]^T, 768 blocks = 3/CU
  gemm_bt<3><<<dim3(32, 24), 256, 0, stream>>>(hs_b, wq_b, qp, kp, vt, 4096, 3072, 2048);

  rope_apply<8><<<16384, 256, 0, stream>>>(qp, tab);
  rope_apply<2><<<4096, 256, 0, stream>>>(kp, tab);

  attn<<<256, 256, 0, stream>>>(qp, kp, vt, aout);

  gemm_bt<2><<<dim3(32, 16), 256, 0, stream>>>(aout, wo_b, out, nullptr, nullptr, 4096, 2048, 2048);
}

// Round 9
// 340.549 us; speedup vs baseline: 1.5833x; 1.1612x over previous
//
#include <hip/hip_runtime.h>
#include <hip/hip_bf16.h>

typedef __bf16 bf16;
typedef bf16 bf16x8 __attribute__((ext_vector_type(8)));
typedef bf16 bf16x4 __attribute__((ext_vector_type(4)));
typedef float f32x4 __attribute__((ext_vector_type(4)));

#define SEQ 2048
#define HID 2048

__device__ __forceinline__ void gload16(const bf16* gsrc, bf16* ldst) {
  __builtin_amdgcn_global_load_lds(
      (const __attribute__((address_space(1))) unsigned int*)gsrc,
      (__attribute__((address_space(3))) unsigned int*)ldst, 16, 0, 0);
}

__device__ __forceinline__ f32x4 mfma16(bf16x8 a, bf16x8 b, f32x4 c) {
  return __builtin_amdgcn_mfma_f32_16x16x32_bf16(a, b, c, 0, 0, 0);
}

// ---------------- cast f32 -> bf16 (vectorized) ----------------
__global__ void cast_bf16(const float* __restrict__ in, bf16* __restrict__ out, int n4) {
  int i = blockIdx.x * 256 + threadIdx.x;
  if (i >= n4) return;
  float4 v = ((const float4*)in)[i];
  bf16x4 o = { (bf16)v.x, (bf16)v.y, (bf16)v.z, (bf16)v.w };
  *(bf16x4*)(out + (size_t)i * 4) = o;
}

// ---------------- rope cos/sin table ----------------
__global__ void rope_table(float2* __restrict__ tab) {
  int i = blockIdx.x * 256 + threadIdx.x;   // 0..262143
  int s = i >> 7, dp = i & 127;
  float invf = powf(10000.0f, -(float)dp * (1.0f / 128.0f));
  float f = (float)s * invf;
  tab[i] = make_float2(cosf(f), sinf(f));
}

// ---------------- rope apply, in place on [4096][H*256] bf16 ----------------
template <int H>
__global__ void rope_apply(bf16* __restrict__ X, const float2* __restrict__ tab) {
  int i = blockIdx.x * 256 + threadIdx.x;
  int dp = i & 127;
  int t = i >> 7;              // t = row*H + h
  int h = t & (H - 1);
  int row = t / H;             // row = b*SEQ + s
  int s = row & (SEQ - 1);
  size_t base = (size_t)row * (H * 256) + h * 256;
  float2 cs = tab[s * 128 + dp];
  float x1 = (float)X[base + dp], x2 = (float)X[base + dp + 128];
  X[base + dp]       = (bf16)(x1 * cs.x - x2 * cs.y);
  X[base + dp + 128] = (bf16)(x2 * cs.x + x1 * cs.y);
}

// ---------------- GEMM: C[M][N] = A[M][K] @ B[N][K]^T ----------------
// EPI 2: f32 out to C.
// EPI 3: fused QKV routing: gcol<2048 -> q (bf16, C), <2560 -> k (bf16, C2),
//        else -> v transposed Vt[b][kv][d][s] (bf16, C3).
template <int EPI>
__global__ void gemm_bt(const bf16* __restrict__ A, const bf16* __restrict__ B,
                        void* __restrict__ C, void* __restrict__ C2,
                        void* __restrict__ C3, int M, int N, int K) {
  __shared__ __align__(16) bf16 la[128 * 64];
  __shared__ __align__(16) bf16 lb[128 * 64];
  const int tid = threadIdx.x;
  const int w = tid >> 6, l = tid & 63;
  const int lr = l & 15, lg = l >> 4;
  const int brow = blockIdx.x * 128, bcol = blockIdx.y * 128;
  const int wr = w >> 1, wc = w & 1;
  f32x4 acc[4][4];
  const f32x4 zero = {0.f, 0.f, 0.f, 0.f};
#pragma unroll
  for (int m = 0; m < 4; ++m)
#pragma unroll
    for (int n = 0; n < 4; ++n) acc[m][n] = zero;

  for (int k0 = 0; k0 < K; k0 += 64) {
#pragma unroll
    for (int p = 0; p < 4; ++p) {
      int gid = (p * 4 + w) * 64 + l;           // granule id, 16B each
      int row = gid >> 3, col = (gid & 7) * 8;  // [128][64] bf16 tile
      gload16(&A[(size_t)(brow + row) * K + k0 + col], &la[(size_t)(p * 4 + w) * 512]);
      gload16(&B[(size_t)(bcol + row) * K + k0 + col], &lb[(size_t)(p * 4 + w) * 512]);
    }
    __syncthreads();
#pragma unroll
    for (int kk = 0; kk < 2; ++kk) {
      bf16x8 af[4], bfr[4];
#pragma unroll
      for (int m = 0; m < 4; ++m)
        af[m] = *(const bf16x8*)&la[(wr * 64 + m * 16 + lr) * 64 + kk * 32 + lg * 8];
#pragma unroll
      for (int n = 0; n < 4; ++n)
        bfr[n] = *(const bf16x8*)&lb[(wc * 64 + n * 16 + lr) * 64 + kk * 32 + lg * 8];
#pragma unroll
      for (int m = 0; m < 4; ++m)
#pragma unroll
        for (int n = 0; n < 4; ++n)
          acc[m][n] = mfma16(af[m], bfr[n], acc[m][n]);
    }
    __syncthreads();
  }

#pragma unroll
  for (int m = 0; m < 4; ++m) {
#pragma unroll
    for (int n = 0; n < 4; ++n) {
#pragma unroll
      for (int r = 0; r < 4; ++r) {
        int grow = brow + wr * 64 + m * 16 + lg * 4 + r;
        int gcol = bcol + wc * 64 + n * 16 + lr;
        float v = acc[m][n][r];
        if constexpr (EPI == 2) {
          ((float*)C)[(size_t)grow * N + gcol] = v;
        } else {  // EPI == 3, branch is block-uniform (bcol multiple of 128)
          if (gcol < 2048) {
            ((bf16*)C)[(size_t)grow * 2048 + gcol] = (bf16)v;
          } else if (gcol < 2560) {
            ((bf16*)C2)[(size_t)grow * 512 + (gcol - 2048)] = (bf16)v;
          } else {
            int kvcol = gcol - 2560;
            int b = grow >> 11, s = grow & (SEQ - 1);
            int kv = kvcol >> 8, d = kvcol & 255;
            ((bf16*)C3)[(((size_t)(b * 2 + kv)) * 256 + d) * SEQ + s] = (bf16)v;
          }
        }
      }
    }
  }
}

// ---------------- attention ----------------
// R5 occupancy structure (verified): grid 512 XCD-remapped, 4 waves x 16q,
// single-buffered K/V (72KB LDS -> 2 blocks/CU = 2 waves/SIMD).
// New: QK^T computed operand-SWAPPED: sc = mfma(kf, qf) = S^T, so each lane
// holds P(q = lr, t = n*16+lg*4+r) -> 4 consecutive t -> P-write packs into
// ds_write_b64 (8 writes/kt instead of 32 scalar). Rowsum becomes lane-local
// per q=lr: 2 shfl_xor (16,32) + 4 broadcast shuffles at the end.
// Swizzles (verified round 5): linear LDS dest + inverse-swizzled global
// source + swizzled read; P swizzled at 16B-granule granularity.
__global__ __launch_bounds__(256, 2)
void attn(const bf16* __restrict__ Qp, const bf16* __restrict__ Kp,
          const bf16* __restrict__ Vt, bf16* __restrict__ Aout) {
  __shared__ __align__(16) bf16 Kl[64 * 256];   // [t][d] 32KB, swizzled
  __shared__ __align__(16) bf16 Vl[256 * 64];   // [d][t] 32KB, swizzled
  __shared__ __align__(16) bf16 Pl[64 * 64];    // [q][t]  8KB, swizzled
  const int tid = threadIdx.x, w = tid >> 6, l = tid & 63;
  const int lr = l & 15, lg = l >> 4;
  // XCD remap: lin -> (xcd = lin&7, slot = lin>>3); work = xcd*64+slot.
  const int lin = blockIdx.x;
  const int work = (lin & 7) * 64 + (lin >> 3);
  const int bh = work >> 5;
  const int b = bh >> 3, h = bh & 7, kv = h >> 2;
  const int q0 = (work & 31) * 64;

  const bf16* qbase = Qp + ((size_t)(b * SEQ + q0 + w * 16 + lr)) * HID + h * 256;
  bf16x8 qf[8];
#pragma unroll
  for (int kc = 0; kc < 8; ++kc) qf[kc] = *(const bf16x8*)(qbase + kc * 32 + lg * 8);

  const f32x4 zero = {0.f, 0.f, 0.f, 0.f};
  f32x4 outa[16];
#pragma unroll
  for (int n = 0; n < 16; ++n) outa[n] = zero;
  float rs = 0.f;   // partial rowsum for q-row (w*16 + lr)

  const bf16* kslab = Kp + (size_t)(b * SEQ) * 512 + kv * 256;
  const bf16* vslab = Vt + (size_t)((b * 2 + kv) * 256) * SEQ;

  for (int kt = 0; kt < 32; ++kt) {
    const int t0 = kt * 64;
#pragma unroll
    for (int p = 0; p < 8; ++p) {
      int gid = p * 256 + w * 64 + l;
      // K tile [64][256]: 32 granules/row; source granule = g ^ (row&7)
      {
        int row = gid >> 5, g = gid & 31;
        gload16(kslab + (size_t)(t0 + row) * 512 + ((g ^ (row & 7)) * 8),
                &Kl[(p * 256 + w * 64) * 8]);
      }
      // Vt tile [256][64]: 8 granules/row; source granule = g ^ (row&7)
      {
        int row = gid >> 3, g = gid & 7;
        gload16(vslab + (size_t)row * SEQ + t0 + ((g ^ (row & 7)) * 8),
                &Vl[(p * 256 + w * 64) * 8]);
      }
    }
    __syncthreads();

    // QK^T swapped: sc[n] = K_tile . Q^T -> lane holds S(q = w*16+lr, t = n*16+lg*4+r)
    f32x4 sc[4];
#pragma unroll
    for (int n = 0; n < 4; ++n) sc[n] = zero;
#pragma unroll
    for (int kc = 0; kc < 8; ++kc) {
#pragma unroll
      for (int n = 0; n < 4; ++n) {
        bf16x8 kf = *(const bf16x8*)&Kl[(n * 16 + lr) * 256 + (((kc * 4 + lg) ^ (lr & 7)) * 8)];
        sc[n] = mfma16(kf, qf[kc], sc[n]);
      }
    }

    // softcap + exp, fixed max 50: p = exp(50*tanh(s/50) - 50) = exp(-100/(e^{s/25}+1))
    // s = raw * 0.0625 -> e1 = exp(raw * 0.0025). 4 consecutive t per lane -> b64 write.
#pragma unroll
    for (int n = 0; n < 4; ++n) {
      bf16x4 pv;
#pragma unroll
      for (int r = 0; r < 4; ++r) {
        float e1 = __expf(sc[n][r] * 0.0025f);
        float p = __expf(-100.0f * __builtin_amdgcn_rcpf(e1 + 1.0f));
        rs += p;
        pv[r] = (bf16)p;
      }
      // P(q=w*16+lr, t = n*16+lg*4 .. +3); granule = n*2+(lg>>1), ^ (row&7)
      int prow = w * 16 + lr;
      int g = (n * 2 + (lg >> 1)) ^ (lr & 7);
      *(bf16x4*)&Pl[prow * 64 + g * 8 + (lg & 1) * 4] = pv;
    }

    // PV: out += P[16q][64t] @ Vt[256d][64t]^T  (unchanged layout)
#pragma unroll
    for (int kc2 = 0; kc2 < 2; ++kc2) {
      bf16x8 pf = *(const bf16x8*)&Pl[(w * 16 + lr) * 64 + (((kc2 * 4 + lg) ^ (lr & 7)) * 8)];
#pragma unroll
      for (int n = 0; n < 16; ++n) {
        bf16x8 vf = *(const bf16x8*)&Vl[(n * 16 + lr) * 64 + (((kc2 * 4 + lg) ^ (lr & 7)) * 8)];
        outa[n] = mfma16(pf, vf, outa[n]);
      }
    }
    __syncthreads();
  }

  // rowsum: lanes lr, lr+16, lr+32, lr+48 hold partials for q-row w*16+lr
  rs += __shfl_xor(rs, 16);
  rs += __shfl_xor(rs, 32);
  float inv = 1.0f / rs;          // inv for q-row w*16+lr
  float invr[4];
#pragma unroll
  for (int r = 0; r < 4; ++r) invr[r] = __shfl(inv, lg * 4 + r, 16);  // inv for q-row w*16+lg*4+r

  bf16* obase = Aout + ((size_t)(b * SEQ + q0 + w * 16 + lg * 4)) * HID + h * 256 + lr;
#pragma unroll
  for (int n = 0; n < 16; ++n)
#pragma unroll
    for (int r = 0; r < 4; ++r)
      obase[(size_t)r * HID + n * 16] = (bf16)(outa[n][r] * invr[r]);
}

// ---------------- launch ----------------
extern "C" void kernel_launch(void* const* d_in, const int* in_sizes, int n_in,
                              void* d_out, int out_size, void* d_ws, size_t ws_size,
                              hipStream_t stream) {
  const float* hs = (const float*)d_in[0];
  const float* Wq = (const float*)d_in[1];
  const float* Wk = (const float*)d_in[2];
  const float* Wv = (const float*)d_in[3];
  const float* Wo = (const float*)d_in[4];
  float* out = (float*)d_out;
  char* ws = (char*)d_ws;

  bf16* hs_b  = (bf16*)(ws + 0);          // 16.8MB, reused as attn-out after QKV GEMM
  bf16* wq_b  = (bf16*)(ws + 16777216);   // 8.4MB  } contiguous [3072][2048]
  bf16* wk_b  = (bf16*)(ws + 25165824);   // 2.1MB  } for the fused QKV GEMM
  bf16* wv_b  = (bf16*)(ws + 27262976);   // 2.1MB  }
  bf16* wo_b  = (bf16*)(ws + 29360128);   // 8.4MB
  bf16* qp    = (bf16*)(ws + 37748736);   // 16.8MB  Q proj (roped in place)
  bf16* kp    = (bf16*)(ws + 54525952);   // 4.2MB   K proj (roped in place)
  bf16* vt    = (bf16*)(ws + 58720256);   // 4.2MB   V transposed [b][kv][d][s]
  float2* tab = (float2*)(ws + 62914560); // 2MB     rope table
  bf16* aout  = hs_b;

  cast_bf16<<<8192, 256, 0, stream>>>(hs, hs_b, 2097152);
  cast_bf16<<<4096, 256, 0, stream>>>(Wq, wq_b, 1048576);
  cast_bf16<<<1024, 256, 0, stream>>>(Wk, wk_b, 262144);
  cast_bf16<<<1024, 256, 0, stream>>>(Wv, wv_b, 262144);
  cast_bf16<<<4096, 256, 0, stream>>>(Wo, wo_b, 1048576);
  rope_table<<<1024, 256, 0, stream>>>(tab);

  // fused QKV: C[4096][3072] = hs_b @ [wq|wk|wv]^T, 768 blocks = 3/CU
  gemm_bt<3><<<dim3(32, 24), 256, 0, stream>>>(hs_b, wq_b, qp, kp, vt, 4096, 3072, 2048);

  rope_apply<8><<<16384, 256, 0, stream>>>(qp, tab);
  rope_apply<2><<<4096, 256, 0, stream>>>(kp, tab);

  attn<<<512, 256, 0, stream>>>(qp, kp, vt, aout);

  gemm_bt<2><<<dim3(32, 16), 256, 0, stream>>>(aout, wo_b, out, nullptr, nullptr, 4096, 2048, 2048);
}